// Round 13
// baseline (136.973 us; speedup 1.0000x reference)
//
#include <hip/hip_runtime.h>

#define NM 23        // 3*K - 1, K = 8

typedef short short8 __attribute__((ext_vector_type(8)));
typedef float f32x4 __attribute__((ext_vector_type(4)));

__device__ __forceinline__ float softplus_f(float v) {
  return fmaxf(v, 0.f) + __logf(1.f + __expf(-fabsf(v)));
}

__device__ __forceinline__ unsigned short bf16_rne(float x) {
  unsigned u = __float_as_uint(x);
  u += 0x7FFFu + ((u >> 16) & 1u);
  return (unsigned short)(u >> 16);
}

// ---------------------------------------------------------------------------
// Prep (R11-validated): pre-masked L1/L2 weights + W3 as MFMA B-fragments
// (bf16 hi/lo split). B[k][n]: n=lane&15, k=(lane>>4)*8+j; n = m*64+d.
// Stored lane-contiguous 16B. Coverage: 184*256 = 47104 exact.
// ---------------------------------------------------------------------------
__global__ __launch_bounds__(256) void prep_kernel(
    const float* __restrict__ W1, const float* __restrict__ W2,
    const float* __restrict__ W3,
    float* __restrict__ W1t, float* __restrict__ W2t,
    unsigned short* __restrict__ Bhi, unsigned short* __restrict__ Blo) {
  const int idx = blockIdx.x * 256 + threadIdx.x;
  if (idx < 64 * 64) {                  // W1t[d][i] = mask * W1[i][d]
    const int d = idx >> 6, i = idx & 63;
    W1t[idx] = ((i % 63) >= d) ? W1[i * 64 + d] : 0.f;
  }
  if (idx < 64 * 32) {                  // W2t[i][j] = mask * W2[j][i]
    const int i = idx >> 5, j = idx & 31;
    W2t[idx] = ((i % 63) <= j) ? W2[j * 64 + i] : 0.f;
  }
  if (idx < 92 * 64 * 8) {              // B fragments
    const int nt = idx >> 9;
    const int rem = idx & 511;
    const int lane = rem >> 3, j = rem & 7;
    const int col = lane & 15, quad = lane >> 4;
    const int n = nt * 16 + col;        // n = m*64 + d
    const int d = n & 63;
    const int k = quad * 8 + j;
    const float v = (k < d) ? W3[(size_t)n * 32 + k] : 0.f;
    const unsigned short h = bf16_rne(v);
    const float hf = __uint_as_float(((unsigned)h) << 16);
    Bhi[idx] = h;
    Blo[idx] = bf16_rne(v - hf);
  }
}

// ---------------------------------------------------------------------------
// Fused kernel (R12 structure). KEY R13 CHANGE: no p[NM] register copy --
// spline reads acc[m][reg] (AGPR) directly at each use site, shrinking VGPR
// live ranges. Register budget target: 92 AGPR (acc) + <=78 VGPR <= 170
// -> 3 waves/SIMD under launch_bounds(256,3). R12 measured 84+92=176 -> 2
// waves/SIMD + residual spill (WRITE 16.3 MB vs 8.7 ideal).
// ---------------------------------------------------------------------------
__global__ __launch_bounds__(256, 3) void fused_kernel(
    const float* __restrict__ x,
    const float* __restrict__ W1t, const float* __restrict__ b1,
    const float* __restrict__ W2t, const float* __restrict__ b2,
    const unsigned short* __restrict__ Bhi,
    const unsigned short* __restrict__ Blo,
    const float* __restrict__ b3,
    float* __restrict__ out, float* __restrict__ ldws, int B) {
  __shared__ float xs[64][68];     // x in; z in-place for this block's d-half
  __shared__ float h1s[64][65];
  __shared__ float h2s[64][36];    // stride 36: 16B-aligned b128 A-frag reads
  __shared__ float b3s[32 * NM];   // this d-half's biases: [dl][m]

  const int t = threadIdx.x;
  const int rb = blockIdx.x >> 1;       // row-block
  const int ds = blockIdx.x & 1;        // d-half: d in [ds*32, ds*32+32)
  const int b0 = rb * 64;

  // ---- stage x: 64x64, 4 float4/thread, coalesced ----
  #pragma unroll
  for (int u = 0; u < 4; ++u) {
    const int idx = t + u * 256;
    const int rr = idx >> 4, c4 = (idx & 15) * 4;
    const float4 v = *reinterpret_cast<const float4*>(
        x + (size_t)b0 * 64 + (size_t)idx * 4);
    xs[rr][c4 + 0] = v.x; xs[rr][c4 + 1] = v.y;
    xs[rr][c4 + 2] = v.z; xs[rr][c4 + 3] = v.w;
  }
  // ---- stage b3 for this d-half: b3s[dl*NM+m] = b3[m*64 + ds*32 + dl] ----
  for (int idx = t; idx < 32 * NM; idx += 256) {
    const int dl = idx / NM, m = idx - dl * NM;
    b3s[idx] = b3[m * 64 + ds * 32 + dl];
  }
  __syncthreads();

  const int r  = t & 63;                                  // lane = row
  const int wv = __builtin_amdgcn_readfirstlane(t >> 6);  // wave 0..3

  // ---- layer 1: i in [wv*16, wv*16+16), pure fmac ----
  {
    const int iBase = wv * 16;
    float acc1[16];
    #pragma unroll
    for (int ii = 0; ii < 16; ++ii) acc1[ii] = b1[iBase + ii];
    #pragma unroll 4
    for (int dd = 0; dd < 64; ++dd) {
      const float xv = xs[r][dd];
      const float* wrow = W1t + dd * 64 + iBase;          // uniform s_load
      #pragma unroll
      for (int ii = 0; ii < 16; ++ii) acc1[ii] = fmaf(xv, wrow[ii], acc1[ii]);
    }
    #pragma unroll
    for (int ii = 0; ii < 16; ++ii) h1s[r][iBase + ii] = fmaxf(acc1[ii], 0.f);
  }
  __syncthreads();

  // ---- layer 2: j in [wv*8, wv*8+8), pure fmac ----
  {
    const int jBase = wv * 8;
    float acc2[8];
    #pragma unroll
    for (int jj = 0; jj < 8; ++jj) acc2[jj] = b2[jBase + jj];
    #pragma unroll 4
    for (int i2 = 0; i2 < 64; ++i2) {
      const float hv = h1s[r][i2];
      const float* wrow = W2t + i2 * 32 + jBase;          // uniform s_load
      #pragma unroll
      for (int jj = 0; jj < 8; ++jj) acc2[jj] = fmaf(hv, wrow[jj], acc2[jj]);
    }
    #pragma unroll
    for (int jj = 0; jj < 8; ++jj)
      h2s[r][jBase + jj] = fmaxf(acc2[jj], 0.f);
  }
  __syncthreads();

  // ---- MFMA layer 3 + spline ----
  const int lane = t & 63;
  const int mt   = wv;                  // M-tile: rows mt*16..mt*16+15
  const int col  = lane & 15;
  const int quad = lane >> 4;

  // A fragment: A[m=lane&15][k=quad*8+j] from h2, bf16 hi/lo split
  short8 ahi, alo;
  {
    const int arow = mt * 16 + col;
    const f32x4 a0 = *reinterpret_cast<const f32x4*>(&h2s[arow][quad * 8]);
    const f32x4 a1 = *reinterpret_cast<const f32x4*>(&h2s[arow][quad * 8 + 4]);
    float af[8] = {a0.x, a0.y, a0.z, a0.w, a1.x, a1.y, a1.z, a1.w};
    #pragma unroll
    for (int j = 0; j < 8; ++j) {
      const unsigned short h = bf16_rne(af[j]);
      ahi[j] = (short)h;
      alo[j] = (short)bf16_rne(af[j] - __uint_as_float(((unsigned)h) << 16));
    }
  }

  float ldr[4] = {0.f, 0.f, 0.f, 0.f};

  #pragma unroll 1
  for (int jj = 0; jj < 2; ++jj) {
    const int dc = ds * 2 + jj;                           // d-chunk 0..3
    const int d  = dc * 16 + col;                         // this lane's d
    const int dl = d - ds * 32;                           // 0..31

    // bias pre-folded into accumulator init (C = A*B + bias)
    f32x4 acc[NM];
    #pragma unroll
    for (int m = 0; m < NM; ++m) {
      const float bv = b3s[dl * NM + m];
      acc[m] = (f32x4){bv, bv, bv, bv};
    }
    #pragma unroll
    for (int m = 0; m < NM; ++m) {
      const int nt = 4 * m + dc;
      const size_t off = ((size_t)nt * 64 + lane) * 8;
      const short8 bh = *reinterpret_cast<const short8*>(Bhi + off);
      const short8 bl = *reinterpret_cast<const short8*>(Blo + off);
      acc[m] = __builtin_amdgcn_mfma_f32_16x16x32_bf16(ahi, bh, acc[m], 0, 0, 0);
      acc[m] = __builtin_amdgcn_mfma_f32_16x16x32_bf16(alo, bh, acc[m], 0, 0, 0);
      acc[m] = __builtin_amdgcn_mfma_f32_16x16x32_bf16(ahi, bl, acc[m], 0, 0, 0);
    }

    // spline: 4 rows per lane (C rows quad*4+reg), this lane's d.
    // acc[m][reg] read DIRECTLY (lazy AGPR->VGPR) -- no p[] copy.
    #pragma unroll
    for (int reg = 0; reg < 4; ++reg) {
      const int row = mt * 16 + quad * 4 + reg;

      const float xv = xs[row][d];
      const float xc = fminf(fmaxf(xv, -3.f), 3.f);

      float mw = acc[0][reg];
      #pragma unroll
      for (int k = 1; k < 8; ++k) mw = fmaxf(mw, acc[k][reg]);
      float ew[8], sw = 0.f;
      #pragma unroll
      for (int k = 0; k < 8; ++k) {
        ew[k] = __expf(acc[k][reg] - mw); sw += ew[k];
      }
      const float invw = 1.f / sw;

      float mh = acc[8][reg];
      #pragma unroll
      for (int k = 1; k < 8; ++k) mh = fmaxf(mh, acc[8 + k][reg]);
      float eh[8], sh = 0.f;
      #pragma unroll
      for (int k = 0; k < 8; ++k) {
        eh[k] = __expf(acc[8 + k][reg] - mh); sh += eh[k];
      }
      const float invh = 1.f / sh;

      const float WSC = 1.0f - 1e-3f * 8.0f;
      float cumw[9], cumh[9];
      cumw[0] = -3.f; cumh[0] = -3.f;
      float cw = 0.f, ch = 0.f;
      #pragma unroll
      for (int k = 0; k < 7; ++k) {
        cw += 1e-3f + WSC * (ew[k] * invw);
        ch += 1e-3f + WSC * (eh[k] * invh);
        cumw[k + 1] = fmaf(6.f, cw, -3.f);
        cumh[k + 1] = fmaf(6.f, ch, -3.f);
      }
      cumw[8] = 3.f; cumh[8] = 3.f;

      float derivs[9];
      derivs[0] = 1.f; derivs[8] = 1.f;
      #pragma unroll
      for (int k = 0; k < 7; ++k)
        derivs[k + 1] = 1e-3f + softplus_f(acc[16 + k][reg]);

      float xk = cumw[0], xk1 = cumw[1];
      float yk = cumh[0], yk1 = cumh[1];
      float dk = derivs[0], dk1 = derivs[1];
      #pragma unroll
      for (int k = 1; k < 8; ++k) {
        const bool s = xc >= cumw[k] + 1e-6f;
        xk  = s ? cumw[k]       : xk;
        xk1 = s ? cumw[k + 1]   : xk1;
        yk  = s ? cumh[k]       : yk;
        yk1 = s ? cumh[k + 1]   : yk1;
        dk  = s ? derivs[k]     : dk;
        dk1 = s ? derivs[k + 1] : dk1;
      }

      const float wk = xk1 - xk, hk = yk1 - yk;
      const float invwk = 1.f / wk;
      const float delta = hk * invwk;
      const float theta = (xc - xk) * invwk;
      const float omt = 1.f - theta;
      const float tt = theta * omt;
      const float th2 = theta * theta;
      const float num = hk * (delta * th2 + dk * tt);
      const float den = delta + (dk + dk1 - 2.f * delta) * tt;
      const float yv = yk + num / den;
      const float dnum = delta * delta * (dk1 * th2 + 2.f * delta * tt + dk * omt * omt);
      const float ldv = __logf(dnum) - 2.f * __logf(den);

      const bool inside = (xv >= -3.f) && (xv <= 3.f);
      xs[row][d] = inside ? yv : xv;        // z in-place (same owner lane)
      ldr[reg] += inside ? ldv : 0.f;
    }
  }

  // ---- log-det: reduce across the 16 cols (lane bits 0..3) ----
  #pragma unroll
  for (int mask = 1; mask <= 8; mask <<= 1) {
    #pragma unroll
    for (int reg = 0; reg < 4; ++reg)
      ldr[reg] += __shfl_xor(ldr[reg], mask, 64);
  }
  __syncthreads();   // all xs spline-writes done before z readback

  if (col == 0) {
    #pragma unroll
    for (int reg = 0; reg < 4; ++reg)
      ldws[(size_t)ds * B + b0 + mt * 16 + quad * 4 + reg] = ldr[reg];
  }

  // ---- coalesced z write: this block's 32 d-columns ----
  #pragma unroll
  for (int u = 0; u < 2; ++u) {
    const int idx = t + u * 256;
    const int rr = idx >> 3, c4 = (idx & 7) * 4;
    const float4 v = make_float4(xs[rr][ds * 32 + c4 + 0],
                                 xs[rr][ds * 32 + c4 + 1],
                                 xs[rr][ds * 32 + c4 + 2],
                                 xs[rr][ds * 32 + c4 + 3]);
    *reinterpret_cast<float4*>(
        out + (size_t)(b0 + rr) * 64 + ds * 32 + c4) = v;
  }
}

// ---------------------------------------------------------------------------
// Sum the 2 d-half log-det partials.
// ---------------------------------------------------------------------------
__global__ __launch_bounds__(256) void ld_reduce(
    const float* __restrict__ ldws, float* __restrict__ out, int B) {
  const int idx = blockIdx.x * 256 + threadIdx.x;
  if (idx < B) out[(size_t)B * 64 + idx] = ldws[idx] + ldws[B + idx];
}

extern "C" void kernel_launch(void* const* d_in, const int* in_sizes, int n_in,
                              void* d_out, int out_size, void* d_ws, size_t ws_size,
                              hipStream_t stream) {
  const float* x  = (const float*)d_in[0];
  const float* W1 = (const float*)d_in[1];
  const float* b1 = (const float*)d_in[2];
  const float* W2 = (const float*)d_in[3];
  const float* b2 = (const float*)d_in[4];
  const float* W3 = (const float*)d_in[5];
  const float* b3 = (const float*)d_in[6];
  float* out = (float*)d_out;
  char* ws   = (char*)d_ws;

  float* W1t = (float*)ws;                              // 4096 f
  float* W2t = (float*)(ws + 16384);                    // 2048 f
  unsigned short* Bhi = (unsigned short*)(ws + 24576);  // 47104 u16
  unsigned short* Blo = (unsigned short*)(ws + 118784); // 47104 u16
  float* ldws = (float*)(ws + 212992);                  // 2*B floats

  const int B = in_sizes[0] / 64;        // 32768

  prep_kernel<<<184, 256, 0, stream>>>(W1, W2, W3, W1t, W2t, Bhi, Blo);

  fused_kernel<<<(B / 64) * 2, 256, 0, stream>>>(
      x, W1t, b1, W2t, b2, Bhi, Blo, b3, out, ldws, B);

  ld_reduce<<<(B + 255) / 256, 256, 0, stream>>>(ldws, out, B);
}

// Round 14
// 131.643 us; speedup vs baseline: 1.0405x; 1.0405x over previous
//
#include <hip/hip_runtime.h>

#define NM 23        // 3*K - 1, K = 8

typedef short short8 __attribute__((ext_vector_type(8)));
typedef float f32x4 __attribute__((ext_vector_type(4)));

__device__ __forceinline__ float softplus_f(float v) {
  return fmaxf(v, 0.f) + __logf(1.f + __expf(-fabsf(v)));
}

__device__ __forceinline__ unsigned short bf16_rne(float x) {
  unsigned u = __float_as_uint(x);
  u += 0x7FFFu + ((u >> 16) & 1u);
  return (unsigned short)(u >> 16);
}

// ---------------------------------------------------------------------------
// Prep (R11-validated): pre-masked L1/L2 weights + W3 as MFMA B-fragments
// (bf16 hi/lo split). B[k][n]: n=lane&15, k=(lane>>4)*8+j; n = m*64+d.
// Stored lane-contiguous 16B. Coverage: 184*256 = 47104 exact.
// ---------------------------------------------------------------------------
__global__ __launch_bounds__(256) void prep_kernel(
    const float* __restrict__ W1, const float* __restrict__ W2,
    const float* __restrict__ W3,
    float* __restrict__ W1t, float* __restrict__ W2t,
    unsigned short* __restrict__ Bhi, unsigned short* __restrict__ Blo) {
  const int idx = blockIdx.x * 256 + threadIdx.x;
  if (idx < 64 * 64) {                  // W1t[d][i] = mask * W1[i][d]
    const int d = idx >> 6, i = idx & 63;
    W1t[idx] = ((i % 63) >= d) ? W1[i * 64 + d] : 0.f;
  }
  if (idx < 64 * 32) {                  // W2t[i][j] = mask * W2[j][i]
    const int i = idx >> 5, j = idx & 31;
    W2t[idx] = ((i % 63) <= j) ? W2[j * 64 + i] : 0.f;
  }
  if (idx < 92 * 64 * 8) {              // B fragments
    const int nt = idx >> 9;
    const int rem = idx & 511;
    const int lane = rem >> 3, j = rem & 7;
    const int col = lane & 15, quad = lane >> 4;
    const int n = nt * 16 + col;        // n = m*64 + d
    const int d = n & 63;
    const int k = quad * 8 + j;
    const float v = (k < d) ? W3[(size_t)n * 32 + k] : 0.f;
    const unsigned short h = bf16_rne(v);
    const float hf = __uint_as_float(((unsigned)h) << 16);
    Bhi[idx] = h;
    Blo[idx] = bf16_rne(v - hf);
  }
}

// ---------------------------------------------------------------------------
// Fused kernel (R12 structure, p[] copy restored). R14 CHANGE:
// __launch_bounds__(256, 2). Live set = 92 AGPR (acc[23]x4) + ~84 VGPR =
// 176 regs. R12/R13's (256,3) demanded <=170 -> compiler spilled (~20 MB
// scratch traffic) AND still ran at 2 waves/SIMD. At (256,2) the budget is
// 256: everything fits, zero scratch, same occupancy.
// ---------------------------------------------------------------------------
__global__ __launch_bounds__(256, 2) void fused_kernel(
    const float* __restrict__ x,
    const float* __restrict__ W1t, const float* __restrict__ b1,
    const float* __restrict__ W2t, const float* __restrict__ b2,
    const unsigned short* __restrict__ Bhi,
    const unsigned short* __restrict__ Blo,
    const float* __restrict__ b3,
    float* __restrict__ out, float* __restrict__ ldws, int B) {
  __shared__ float xs[64][68];     // x in; z in-place for this block's d-half
  __shared__ float h1s[64][65];
  __shared__ float h2s[64][36];    // stride 36: 16B-aligned b128 A-frag reads
  __shared__ float b3s[32 * NM];   // this d-half's biases: [dl][m]

  const int t = threadIdx.x;
  const int rb = blockIdx.x >> 1;       // row-block
  const int ds = blockIdx.x & 1;        // d-half: d in [ds*32, ds*32+32)
  const int b0 = rb * 64;

  // ---- stage x: 64x64, 4 float4/thread, coalesced ----
  #pragma unroll
  for (int u = 0; u < 4; ++u) {
    const int idx = t + u * 256;
    const int rr = idx >> 4, c4 = (idx & 15) * 4;
    const float4 v = *reinterpret_cast<const float4*>(
        x + (size_t)b0 * 64 + (size_t)idx * 4);
    xs[rr][c4 + 0] = v.x; xs[rr][c4 + 1] = v.y;
    xs[rr][c4 + 2] = v.z; xs[rr][c4 + 3] = v.w;
  }
  // ---- stage b3 for this d-half: b3s[dl*NM+m] = b3[m*64 + ds*32 + dl] ----
  for (int idx = t; idx < 32 * NM; idx += 256) {
    const int dl = idx / NM, m = idx - dl * NM;
    b3s[idx] = b3[m * 64 + ds * 32 + dl];
  }
  __syncthreads();

  const int r  = t & 63;                                  // lane = row
  const int wv = __builtin_amdgcn_readfirstlane(t >> 6);  // wave 0..3

  // ---- layer 1: i in [wv*16, wv*16+16), pure fmac ----
  {
    const int iBase = wv * 16;
    float acc1[16];
    #pragma unroll
    for (int ii = 0; ii < 16; ++ii) acc1[ii] = b1[iBase + ii];
    #pragma unroll 4
    for (int dd = 0; dd < 64; ++dd) {
      const float xv = xs[r][dd];
      const float* wrow = W1t + dd * 64 + iBase;          // uniform s_load
      #pragma unroll
      for (int ii = 0; ii < 16; ++ii) acc1[ii] = fmaf(xv, wrow[ii], acc1[ii]);
    }
    #pragma unroll
    for (int ii = 0; ii < 16; ++ii) h1s[r][iBase + ii] = fmaxf(acc1[ii], 0.f);
  }
  __syncthreads();

  // ---- layer 2: j in [wv*8, wv*8+8), pure fmac ----
  {
    const int jBase = wv * 8;
    float acc2[8];
    #pragma unroll
    for (int jj = 0; jj < 8; ++jj) acc2[jj] = b2[jBase + jj];
    #pragma unroll 4
    for (int i2 = 0; i2 < 64; ++i2) {
      const float hv = h1s[r][i2];
      const float* wrow = W2t + i2 * 32 + jBase;          // uniform s_load
      #pragma unroll
      for (int jj = 0; jj < 8; ++jj) acc2[jj] = fmaf(hv, wrow[jj], acc2[jj]);
    }
    #pragma unroll
    for (int jj = 0; jj < 8; ++jj)
      h2s[r][jBase + jj] = fmaxf(acc2[jj], 0.f);
  }
  __syncthreads();

  // ---- MFMA layer 3 + spline ----
  const int lane = t & 63;
  const int mt   = wv;                  // M-tile: rows mt*16..mt*16+15
  const int col  = lane & 15;
  const int quad = lane >> 4;

  // A fragment: A[m=lane&15][k=quad*8+j] from h2, bf16 hi/lo split
  short8 ahi, alo;
  {
    const int arow = mt * 16 + col;
    const f32x4 a0 = *reinterpret_cast<const f32x4*>(&h2s[arow][quad * 8]);
    const f32x4 a1 = *reinterpret_cast<const f32x4*>(&h2s[arow][quad * 8 + 4]);
    float af[8] = {a0.x, a0.y, a0.z, a0.w, a1.x, a1.y, a1.z, a1.w};
    #pragma unroll
    for (int j = 0; j < 8; ++j) {
      const unsigned short h = bf16_rne(af[j]);
      ahi[j] = (short)h;
      alo[j] = (short)bf16_rne(af[j] - __uint_as_float(((unsigned)h) << 16));
    }
  }

  float ldr[4] = {0.f, 0.f, 0.f, 0.f};

  #pragma unroll 1
  for (int jj = 0; jj < 2; ++jj) {
    const int dc = ds * 2 + jj;                           // d-chunk 0..3
    const int d  = dc * 16 + col;                         // this lane's d
    const int dl = d - ds * 32;                           // 0..31

    // bias pre-folded into accumulator init (C = A*B + bias)
    f32x4 acc[NM];
    #pragma unroll
    for (int m = 0; m < NM; ++m) {
      const float bv = b3s[dl * NM + m];
      acc[m] = (f32x4){bv, bv, bv, bv};
    }
    #pragma unroll
    for (int m = 0; m < NM; ++m) {
      const int nt = 4 * m + dc;
      const size_t off = ((size_t)nt * 64 + lane) * 8;
      const short8 bh = *reinterpret_cast<const short8*>(Bhi + off);
      const short8 bl = *reinterpret_cast<const short8*>(Blo + off);
      acc[m] = __builtin_amdgcn_mfma_f32_16x16x32_bf16(ahi, bh, acc[m], 0, 0, 0);
      acc[m] = __builtin_amdgcn_mfma_f32_16x16x32_bf16(alo, bh, acc[m], 0, 0, 0);
      acc[m] = __builtin_amdgcn_mfma_f32_16x16x32_bf16(ahi, bl, acc[m], 0, 0, 0);
    }

    // spline: 4 rows per lane (C rows quad*4+reg), this lane's d
    #pragma unroll
    for (int reg = 0; reg < 4; ++reg) {
      const int row = mt * 16 + quad * 4 + reg;

      float p[NM];
      #pragma unroll
      for (int m = 0; m < NM; ++m) p[m] = acc[m][reg];

      const float xv = xs[row][d];
      const float xc = fminf(fmaxf(xv, -3.f), 3.f);

      float mw = p[0];
      #pragma unroll
      for (int k = 1; k < 8; ++k) mw = fmaxf(mw, p[k]);
      float ew[8], sw = 0.f;
      #pragma unroll
      for (int k = 0; k < 8; ++k) { ew[k] = __expf(p[k] - mw); sw += ew[k]; }
      const float invw = 1.f / sw;

      float mh = p[8];
      #pragma unroll
      for (int k = 1; k < 8; ++k) mh = fmaxf(mh, p[8 + k]);
      float eh[8], sh = 0.f;
      #pragma unroll
      for (int k = 0; k < 8; ++k) { eh[k] = __expf(p[8 + k] - mh); sh += eh[k]; }
      const float invh = 1.f / sh;

      const float WSC = 1.0f - 1e-3f * 8.0f;
      float cumw[9], cumh[9];
      cumw[0] = -3.f; cumh[0] = -3.f;
      float cw = 0.f, ch = 0.f;
      #pragma unroll
      for (int k = 0; k < 7; ++k) {
        cw += 1e-3f + WSC * (ew[k] * invw);
        ch += 1e-3f + WSC * (eh[k] * invh);
        cumw[k + 1] = fmaf(6.f, cw, -3.f);
        cumh[k + 1] = fmaf(6.f, ch, -3.f);
      }
      cumw[8] = 3.f; cumh[8] = 3.f;

      float derivs[9];
      derivs[0] = 1.f; derivs[8] = 1.f;
      #pragma unroll
      for (int k = 0; k < 7; ++k) derivs[k + 1] = 1e-3f + softplus_f(p[16 + k]);

      float xk = cumw[0], xk1 = cumw[1];
      float yk = cumh[0], yk1 = cumh[1];
      float dk = derivs[0], dk1 = derivs[1];
      #pragma unroll
      for (int k = 1; k < 8; ++k) {
        const bool s = xc >= cumw[k] + 1e-6f;
        xk  = s ? cumw[k]       : xk;
        xk1 = s ? cumw[k + 1]   : xk1;
        yk  = s ? cumh[k]       : yk;
        yk1 = s ? cumh[k + 1]   : yk1;
        dk  = s ? derivs[k]     : dk;
        dk1 = s ? derivs[k + 1] : dk1;
      }

      const float wk = xk1 - xk, hk = yk1 - yk;
      const float invwk = 1.f / wk;
      const float delta = hk * invwk;
      const float theta = (xc - xk) * invwk;
      const float omt = 1.f - theta;
      const float tt = theta * omt;
      const float th2 = theta * theta;
      const float num = hk * (delta * th2 + dk * tt);
      const float den = delta + (dk + dk1 - 2.f * delta) * tt;
      const float yv = yk + num / den;
      const float dnum = delta * delta * (dk1 * th2 + 2.f * delta * tt + dk * omt * omt);
      const float ldv = __logf(dnum) - 2.f * __logf(den);

      const bool inside = (xv >= -3.f) && (xv <= 3.f);
      xs[row][d] = inside ? yv : xv;        // z in-place (same owner lane)
      ldr[reg] += inside ? ldv : 0.f;
    }
  }

  // ---- log-det: reduce across the 16 cols (lane bits 0..3) ----
  #pragma unroll
  for (int mask = 1; mask <= 8; mask <<= 1) {
    #pragma unroll
    for (int reg = 0; reg < 4; ++reg)
      ldr[reg] += __shfl_xor(ldr[reg], mask, 64);
  }
  __syncthreads();   // all xs spline-writes done before z readback

  if (col == 0) {
    #pragma unroll
    for (int reg = 0; reg < 4; ++reg)
      ldws[(size_t)ds * B + b0 + mt * 16 + quad * 4 + reg] = ldr[reg];
  }

  // ---- coalesced z write: this block's 32 d-columns ----
  #pragma unroll
  for (int u = 0; u < 2; ++u) {
    const int idx = t + u * 256;
    const int rr = idx >> 3, c4 = (idx & 7) * 4;
    const float4 v = make_float4(xs[rr][ds * 32 + c4 + 0],
                                 xs[rr][ds * 32 + c4 + 1],
                                 xs[rr][ds * 32 + c4 + 2],
                                 xs[rr][ds * 32 + c4 + 3]);
    *reinterpret_cast<float4*>(
        out + (size_t)(b0 + rr) * 64 + ds * 32 + c4) = v;
  }
}

// ---------------------------------------------------------------------------
// Sum the 2 d-half log-det partials.
// ---------------------------------------------------------------------------
__global__ __launch_bounds__(256) void ld_reduce(
    const float* __restrict__ ldws, float* __restrict__ out, int B) {
  const int idx = blockIdx.x * 256 + threadIdx.x;
  if (idx < B) out[(size_t)B * 64 + idx] = ldws[idx] + ldws[B + idx];
}

extern "C" void kernel_launch(void* const* d_in, const int* in_sizes, int n_in,
                              void* d_out, int out_size, void* d_ws, size_t ws_size,
                              hipStream_t stream) {
  const float* x  = (const float*)d_in[0];
  const float* W1 = (const float*)d_in[1];
  const float* b1 = (const float*)d_in[2];
  const float* W2 = (const float*)d_in[3];
  const float* b2 = (const float*)d_in[4];
  const float* W3 = (const float*)d_in[5];
  const float* b3 = (const float*)d_in[6];
  float* out = (float*)d_out;
  char* ws   = (char*)d_ws;

  float* W1t = (float*)ws;                              // 4096 f
  float* W2t = (float*)(ws + 16384);                    // 2048 f
  unsigned short* Bhi = (unsigned short*)(ws + 24576);  // 47104 u16
  unsigned short* Blo = (unsigned short*)(ws + 118784); // 47104 u16
  float* ldws = (float*)(ws + 212992);                  // 2*B floats

  const int B = in_sizes[0] / 64;        // 32768

  prep_kernel<<<184, 256, 0, stream>>>(W1, W2, W3, W1t, W2t, Bhi, Blo);

  fused_kernel<<<(B / 64) * 2, 256, 0, stream>>>(
      x, W1t, b1, W2t, b2, Bhi, Blo, b3, out, ldws, B);

  ld_reduce<<<(B + 255) / 256, 256, 0, stream>>>(ldws, out, B);
}